// Round 3
// baseline (181.667 us; speedup 1.0000x reference)
//
#include <hip/hip_runtime.h>
#include <math.h>

// x: (C,H,W) = (256,512,512) f32.  out = 2 * suffix_max_W( suffix_max_H( x ) )
constexpr int C     = 256;
constexpr int H     = 512;
constexpr int W     = 512;
constexpr int RB    = 8;           // rows per half per batch
constexpr int BATCH = 2 * RB;      // 16 rows per batch

// One 1024-thread block per channel (16 waves/CU, ~47% occupancy).
// Two 512-thread halves split each 16-row batch:
//   half 0 (A) = bottom 8 rows: consumes running colmax (gcol), chains,
//                publishes mid-carry (gmid)
//   half 1 (B) = top 8 rows: local 8-row suffix chain in parallel; after
//                bar1 merges gmid and publishes the new running colmax
// Both halves then run their 8 W-suffix-scans concurrently (16 waves of
// shuffle ILP), bar2, cross-wave carry via LDS totals, coalesced store.
// Barrier ordering makes single-buffer gcol/gmid race-free:
//   gcol: write(pre-bar2) -> bar2 -> read(pre-bar1) -> bar1 -> write
//   gmid: write(pre-bar1) -> bar1 -> read(pre-bar2) -> bar2 -> write
__global__ __launch_bounds__(1024)
void tlc_kernel(const float* __restrict__ x, float* __restrict__ out) {
    const int tid  = threadIdx.x;
    const int half = tid >> 9;         // 0 = bottom rows (A), 1 = top rows (B)
    const int w    = tid & 511;        // column
    const int lane = tid & 63;
    const int wid  = (w >> 6);         // wave index within the half: 0..7
    const int c    = blockIdx.x;

    __shared__ float gcol[512];        // running colmax (rows below batch)
    __shared__ float gmid[512];        // colmax incl. bottom half of batch
    __shared__ float totals[2][RB][8]; // [half][row][wave] segment maxima

    const float* __restrict__ xc = x   + (size_t)c * H * W;
    float*       __restrict__ oc = out + (size_t)c * H * W;

    // clamped source lanes for the suffix-max butterfly (loop-invariant)
    int s1  = lane + 1;  if (s1  > 63) s1  = 63;
    int s2  = lane + 2;  if (s2  > 63) s2  = 63;
    int s4  = lane + 4;  if (s4  > 63) s4  = 63;
    int s8  = lane + 8;  if (s8  > 63) s8  = 63;
    int s16 = lane + 16; if (s16 > 63) s16 = 63;
    int s32 = lane + 32; if (s32 > 63) s32 = 63;

    if (half == 0) gcol[w] = -INFINITY;
    __syncthreads();

    // this thread's first row of its half-batch: A -> hb+RB, B -> hb
    int rowbase = (H - BATCH) + half * 0 + (half == 0 ? RB : 0);
    // (A owns rows hb+RB..hb+2RB-1 = bottom; B owns hb..hb+RB-1 = top)

    float cur[RB], nxt[RB];
    #pragma unroll
    for (int r = 0; r < RB; ++r)
        cur[r] = xc[(size_t)(rowbase + r) * W + w];

    for (int hb = H - BATCH; hb >= 0; hb -= BATCH, rowbase -= BATCH) {
        // issue next batch's loads immediately — complete under this batch
        if (hb >= BATCH) {
            #pragma unroll
            for (int r = 0; r < RB; ++r)
                nxt[r] = xc[(size_t)(rowbase - BATCH + r) * W + w];
        }

        float v[RB];
        if (half == 0) {
            // A: chain bottom rows with the running colmax, publish mid carry
            float cm = gcol[w];
            #pragma unroll
            for (int r = RB - 1; r >= 0; --r) {
                cm = fmaxf(cm, cur[r]);
                v[r] = cm;
            }
            gmid[w] = cm;
        } else {
            // B: local suffix chain (carry-free, runs concurrently with A)
            float cm = -INFINITY;
            #pragma unroll
            for (int r = RB - 1; r >= 0; --r) {
                cm = fmaxf(cm, cur[r]);
                v[r] = cm;
            }
        }
        __syncthreads();   // bar1: gmid visible; gcol read done before rewrite

        if (half == 1) {
            const float mid = gmid[w];
            #pragma unroll
            for (int r = 0; r < RB; ++r) v[r] = fmaxf(v[r], mid);
            gcol[w] = v[0];             // new running colmax (whole batch)
        }

        // intra-wave inclusive suffix-max; RB independent scans per step
        #pragma unroll
        for (int r = 0; r < RB; ++r) v[r] = fmaxf(v[r], __shfl(v[r], s1));
        #pragma unroll
        for (int r = 0; r < RB; ++r) v[r] = fmaxf(v[r], __shfl(v[r], s2));
        #pragma unroll
        for (int r = 0; r < RB; ++r) v[r] = fmaxf(v[r], __shfl(v[r], s4));
        #pragma unroll
        for (int r = 0; r < RB; ++r) v[r] = fmaxf(v[r], __shfl(v[r], s8));
        #pragma unroll
        for (int r = 0; r < RB; ++r) v[r] = fmaxf(v[r], __shfl(v[r], s16));
        #pragma unroll
        for (int r = 0; r < RB; ++r) v[r] = fmaxf(v[r], __shfl(v[r], s32));

        // publish wave totals (lane 0 holds the whole-wave max after scan)
        if (lane == 0) {
            #pragma unroll
            for (int r = 0; r < RB; ++r)
                totals[half][r][wid] = v[r];
        }
        __syncthreads();   // bar2: totals visible; gcol write visible to A

        // carry for wave `wid` = max of totals of waves wid+1..7 (same half)
        #pragma unroll
        for (int r = 0; r < RB; ++r) {
            const float4 t0 = *(const float4*)&totals[half][r][0];
            const float4 t1 = *(const float4*)&totals[half][r][4];
            float carry = -INFINITY;
            if (wid < 1) carry = fmaxf(carry, t0.y);
            if (wid < 2) carry = fmaxf(carry, t0.z);
            if (wid < 3) carry = fmaxf(carry, t0.w);
            if (wid < 4) carry = fmaxf(carry, t1.x);
            if (wid < 5) carry = fmaxf(carry, t1.y);
            if (wid < 6) carry = fmaxf(carry, t1.z);
            if (wid < 7) carry = fmaxf(carry, t1.w);
            v[r] = fmaxf(v[r], carry);
            oc[(size_t)(rowbase + r) * W + w] = 2.0f * v[r];
        }

        #pragma unroll
        for (int r = 0; r < RB; ++r)
            cur[r] = nxt[r];
    }
}

extern "C" void kernel_launch(void* const* d_in, const int* in_sizes, int n_in,
                              void* d_out, int out_size, void* d_ws, size_t ws_size,
                              hipStream_t stream) {
    const float* x   = (const float*)d_in[0];
    float*       out = (float*)d_out;
    tlc_kernel<<<dim3(C), dim3(1024), 0, stream>>>(x, out);
}

// Round 4
// 114.031 us; speedup vs baseline: 1.5931x; 1.5931x over previous
//
#include <hip/hip_runtime.h>
#include <math.h>

// x: (C,H,W) = (256,512,512) f32.  out = 2 * suffix_max_W( suffix_max_H( x ) )
constexpr int C     = 256;
constexpr int H     = 512;
constexpr int W     = 512;
constexpr int RPW   = 4;            // rows per wave per batch
constexpr int BATCH = 8 * RPW;      // 32 rows per batch (8 waves)

__device__ __forceinline__ float4 fmax4(float4 x, float4 y) {
    return make_float4(fmaxf(x.x, y.x), fmaxf(x.y, y.y),
                       fmaxf(x.z, y.z), fmaxf(x.w, y.w));
}

// One 512-thread block per channel. Each lane owns 8 consecutive columns
// (2 float4), so a full 512-col W suffix-scan lives in ONE wave:
//   7 in-register fmax + 7 shuffles (shift + clamped butterfly).
// Each wave owns 4 rows of a 32-row batch. H-chain = per-wave local suffix
// chain + LDS carry merge (double-buffered -> ONE barrier per 32 rows).
__global__ __launch_bounds__(512)
void tlc_kernel(const float* __restrict__ x, float* __restrict__ out) {
    const int tid  = threadIdx.x;
    const int g    = tid >> 6;        // wave 0..7
    const int lane = tid & 63;
    const int c    = blockIdx.x;
    const int col  = lane * 8;        // first of this lane's 8 columns

    // double-buffered wave column-totals and running colmax (16B/lane stride
    // everywhere -> conflict-free b128)
    __shared__ float4 ltotA[2][8][64], ltotB[2][8][64];
    __shared__ float4 gcolA[2][64],    gcolB[2][64];

    const float* __restrict__ xc = x   + (size_t)c * H * W;
    float*       __restrict__ oc = out + (size_t)c * H * W;

    // clamped source lanes for the suffix butterfly
    const int s1  = min(lane + 1, 63), s2  = min(lane + 2, 63);
    const int s4  = min(lane + 4, 63), s8  = min(lane + 8, 63);
    const int s16 = min(lane + 16, 63), s32 = min(lane + 32, 63);

    if (g == 0) {
        const float4 ninf = make_float4(-INFINITY, -INFINITY, -INFINITY, -INFINITY);
        gcolA[0][lane] = ninf;
        gcolB[0][lane] = ninf;   // ordered before first read by batch-0's barrier
    }

    int   buf = 0;
    int   rowbase = (H - BATCH) + RPW * g;   // this wave's first row of batch
    float4 curA[RPW], curB[RPW], nxtA[RPW], nxtB[RPW];

    #pragma unroll
    for (int r = 0; r < RPW; ++r) {
        const float* p = xc + (size_t)(rowbase + r) * W + col;
        curA[r] = *(const float4*)p;
        curB[r] = *(const float4*)(p + 4);
    }

    for (int hb = H - BATCH; hb >= 0; hb -= BATCH, rowbase -= BATCH) {
        // issue next batch's loads now; they retire under this batch's work
        if (hb >= BATCH) {
            #pragma unroll
            for (int r = 0; r < RPW; ++r) {
                const float* p = xc + (size_t)(rowbase - BATCH + r) * W + col;
                nxtA[r] = *(const float4*)p;
                nxtB[r] = *(const float4*)(p + 4);
            }
        }

        // local H suffix chain over this wave's rows (bottom row = RPW-1)
        float4 pA[RPW], pB[RPW];
        pA[RPW - 1] = curA[RPW - 1];
        pB[RPW - 1] = curB[RPW - 1];
        #pragma unroll
        for (int r = RPW - 2; r >= 0; --r) {
            pA[r] = fmax4(curA[r], pA[r + 1]);
            pB[r] = fmax4(curB[r], pB[r + 1]);
        }

        // publish wave-local column totals
        ltotA[buf][g][lane] = pA[0];
        ltotB[buf][g][lane] = pB[0];
        __syncthreads();   // the only barrier per batch

        // carry = max(running colmax, totals of waves below this one)
        float4 mA = gcolA[buf][lane];
        float4 mB = gcolB[buf][lane];
        for (int gg = g + 1; gg < 8; ++gg) {   // wave-uniform trip count
            mA = fmax4(mA, ltotA[buf][gg][lane]);
            mB = fmax4(mB, ltotB[buf][gg][lane]);
        }

        // wave 0 owns the whole-batch total -> running colmax for next batch
        if (g == 0) {
            gcolA[buf ^ 1][lane] = fmax4(pA[0], mA);
            gcolB[buf ^ 1][lane] = fmax4(pB[0], mB);
        }

        // per-row: merge carry, 1-wave W suffix scan, store
        #pragma unroll
        for (int r = 0; r < RPW; ++r) {
            const float4 vA = fmax4(pA[r], mA);
            const float4 vB = fmax4(pB[r], mB);

            // in-thread suffix over the lane's 8 columns
            const float t7 = vB.w;
            const float t6 = fmaxf(vB.z, t7);
            const float t5 = fmaxf(vB.y, t6);
            const float t4 = fmaxf(vB.x, t5);
            const float t3 = fmaxf(vA.w, t4);
            const float t2 = fmaxf(vA.z, t3);
            const float t1 = fmaxf(vA.y, t2);
            const float t0 = fmaxf(vA.x, t1);

            // exclusive suffix of lane totals: shift by 1, then clamped
            // inclusive butterfly (max over lanes > mine)
            float e = __shfl(t0, s1);
            e = (lane == 63) ? -INFINITY : e;
            e = fmaxf(e, __shfl(e, s1));
            e = fmaxf(e, __shfl(e, s2));
            e = fmaxf(e, __shfl(e, s4));
            e = fmaxf(e, __shfl(e, s8));
            e = fmaxf(e, __shfl(e, s16));
            e = fmaxf(e, __shfl(e, s32));

            float4 oA, oB;
            oA.x = 2.0f * fmaxf(t0, e);
            oA.y = 2.0f * fmaxf(t1, e);
            oA.z = 2.0f * fmaxf(t2, e);
            oA.w = 2.0f * fmaxf(t3, e);
            oB.x = 2.0f * fmaxf(t4, e);
            oB.y = 2.0f * fmaxf(t5, e);
            oB.z = 2.0f * fmaxf(t6, e);
            oB.w = 2.0f * fmaxf(t7, e);

            float* q = oc + (size_t)(rowbase + r) * W + col;
            *(float4*)q       = oA;
            *(float4*)(q + 4) = oB;
        }

        #pragma unroll
        for (int r = 0; r < RPW; ++r) {
            curA[r] = nxtA[r];
            curB[r] = nxtB[r];
        }
        buf ^= 1;
    }
}

extern "C" void kernel_launch(void* const* d_in, const int* in_sizes, int n_in,
                              void* d_out, int out_size, void* d_ws, size_t ws_size,
                              hipStream_t stream) {
    const float* x   = (const float*)d_in[0];
    float*       out = (float*)d_out;
    tlc_kernel<<<dim3(C), dim3(512), 0, stream>>>(x, out);
}